// Round 1
// baseline (366.475 us; speedup 1.0000x reference)
//
#include <hip/hip_runtime.h>
#include <math.h>

#define BATCH   16384
#define DMODEL  1024
#define NSTATE  16
#define LN_EPS  1e-5f

typedef __bf16 bf16x8 __attribute__((ext_vector_type(8)));
typedef float  f32x4  __attribute__((ext_vector_type(4)));

static __device__ __forceinline__ unsigned short f2bf(float v) {
  union { float f; unsigned u; } c; c.f = v;
  unsigned r = c.u + 0x7fffu + ((c.u >> 16) & 1u);  // round-to-nearest-even
  return (unsigned short)(r >> 16);
}
static __device__ __forceinline__ float bf2f(unsigned short h) {
  union { unsigned u; float f; } c; c.u = ((unsigned)h) << 16;
  return c.f;
}

// async global->LDS, 16B per lane; lds dest = wave-uniform base + lane*16
static __device__ __forceinline__ void gload16(const void* g, void* l) {
  __builtin_amdgcn_global_load_lds(
      (const __attribute__((address_space(1))) void*)g,
      (__attribute__((address_space(3))) void*)l, 16, 0, 0);
}

// ---------------- weight hi/lo split ----------------
__global__ __launch_bounds__(256) void split_kernel(
    const float* __restrict__ src, unsigned short* __restrict__ hi,
    unsigned short* __restrict__ lo, int n) {
  int i = blockIdx.x * 256 + threadIdx.x;
  if (i < n) {
    float v = src[i];
    unsigned short h = f2bf(v);
    hi[i] = h;
    lo[i] = f2bf(v - bf2f(h));
  }
}

// ---------------- LayerNorm + xn split ----------------
__global__ __launch_bounds__(256) void ln_kernel(
    const float* __restrict__ x, const float* __restrict__ gamma,
    const float* __restrict__ beta, unsigned short* __restrict__ xnh,
    unsigned short* __restrict__ xnl) {
  const int row = blockIdx.x;
  const int tid = threadIdx.x;
  const float4* xr = (const float4*)(x + (size_t)row * DMODEL);
  float4 v = xr[tid];
  float s = v.x + v.y + v.z + v.w;
  float q = v.x * v.x + v.y * v.y + v.z * v.z + v.w * v.w;
#pragma unroll
  for (int m = 1; m < 64; m <<= 1) {
    s += __shfl_xor(s, m, 64);
    q += __shfl_xor(q, m, 64);
  }
  __shared__ float ws[4], wq[4];
  int w = tid >> 6, l = tid & 63;
  if (l == 0) { ws[w] = s; wq[w] = q; }
  __syncthreads();
  s = ws[0] + ws[1] + ws[2] + ws[3];
  q = wq[0] + wq[1] + wq[2] + wq[3];
  float mu = s * (1.0f / DMODEL);
  float var = q * (1.0f / DMODEL) - mu * mu;
  float rs = rsqrtf(var + LN_EPS);
  float4 g = ((const float4*)gamma)[tid];
  float4 b = ((const float4*)beta)[tid];
  float xn[4];
  xn[0] = (v.x - mu) * rs * g.x + b.x;
  xn[1] = (v.y - mu) * rs * g.y + b.y;
  xn[2] = (v.z - mu) * rs * g.z + b.z;
  xn[3] = (v.w - mu) * rs * g.w + b.w;
  ushort4 hs, ls;
  unsigned short h;
  h = f2bf(xn[0]); hs.x = h; ls.x = f2bf(xn[0] - bf2f(h));
  h = f2bf(xn[1]); hs.y = h; ls.y = f2bf(xn[1] - bf2f(h));
  h = f2bf(xn[2]); hs.z = h; ls.z = f2bf(xn[2] - bf2f(h));
  h = f2bf(xn[3]); hs.w = h; ls.w = f2bf(xn[3] - bf2f(h));
  ((ushort4*)xnh)[(size_t)row * 256 + tid] = hs;
  ((ushort4*)xnl)[(size_t)row * 256 + tid] = ls;
}

// ---------------- split-bf16 GEMM (shared template) ----------------
// C[m,n] = sum_k A[m,k]*B[n,k]  (both operands row-major [rows][K])
// EPI 0: Bm/Cm -> s   EPI 1: softplus/dt -> y (split)   EPI 2: +bias+residual -> out
template <int BM, int BN, int NBN, int WAVES_M, int WAVES_N, int MT, int NT, int EPI>
__global__ __launch_bounds__(WAVES_M * WAVES_N * 64) void gemm_kernel(
    const unsigned short* __restrict__ Ah_g, const unsigned short* __restrict__ Al_g,
    const unsigned short* __restrict__ Bh_g, const unsigned short* __restrict__ Bl_g,
    const float* __restrict__ e0,            // EPI0: bb   EPI1: bdt    EPI2: bo
    const float* __restrict__ e1,            // EPI0: bc   EPI1: D_skip EPI2: x (residual)
    const float* __restrict__ e2,            // EPI1: s
    const unsigned short* __restrict__ e3h,  // EPI1: xnh
    const unsigned short* __restrict__ e3l,  // EPI1: xnl
    unsigned short* __restrict__ outh,       // EPI1: yh
    unsigned short* __restrict__ outl,       // EPI1: yl
    float* __restrict__ outf,                // EPI0: s    EPI2: out
    int K) {
  constexpr int THREADS = WAVES_M * WAVES_N * 64;
  constexpr int GRID = (BATCH / BM) * NBN;
  static_assert(BM == WAVES_M * MT * 16 && BN == WAVES_N * NT * 16, "tile");

  __shared__ char smem[(BM + BN) * 256];
  char* sAh = smem;
  char* sAl = smem + BM * 128;
  char* sBh = smem + BM * 256;
  char* sBl = smem + BM * 256 + BN * 128;

  const int tid = threadIdx.x;
  const int l = tid & 63;
  const int w = tid >> 6;
  const int wm = w / WAVES_N;
  const int wn = w % WAVES_N;

  // bijective XCD swizzle (8 XCDs; GRID % 8 == 0)
  int bid = blockIdx.x;
  int sid = (bid & 7) * (GRID / 8) + (bid >> 3);
  const int bm = sid / NBN;
  const int bn = sid % NBN;
  const int m0 = bm * BM;
  const int n0 = bn * BN;

  f32x4 acc[MT][NT];
  const f32x4 fzero = {0.f, 0.f, 0.f, 0.f};
#pragma unroll
  for (int mi = 0; mi < MT; ++mi)
#pragma unroll
    for (int ni = 0; ni < NT; ++ni) acc[mi][ni] = fzero;

  constexpr int A_LOADS = (BM * 128) / (THREADS * 16);
  constexpr int B_LOADS = (BN * 128) / (THREADS * 16);

  for (int kt = 0; kt < K; kt += 64) {
    // stage (pre-swizzled global source -> linear LDS; swizzle = chunk ^ (row&7))
#pragma unroll
    for (int i = 0; i < A_LOADS; ++i) {
      int q = i * THREADS + tid;
      int row = q >> 3;
      int c = (q & 7) ^ (row & 7);
      size_t goff = (size_t)(m0 + row) * K + kt + c * 8;
      int lbase = i * THREADS * 16 + w * 1024;
      gload16(Ah_g + goff, sAh + lbase);
      gload16(Al_g + goff, sAl + lbase);
    }
#pragma unroll
    for (int i = 0; i < B_LOADS; ++i) {
      int q = i * THREADS + tid;
      int row = q >> 3;
      int c = (q & 7) ^ (row & 7);
      size_t goff = (size_t)(n0 + row) * K + kt + c * 8;
      int lbase = i * THREADS * 16 + w * 1024;
      gload16(Bh_g + goff, sBh + lbase);
      gload16(Bl_g + goff, sBl + lbase);
    }
    __syncthreads();

#pragma unroll
    for (int kk = 0; kk < 2; ++kk) {
      bf16x8 ah[MT], al[MT], bh[NT], bl[NT];
#pragma unroll
      for (int mi = 0; mi < MT; ++mi) {
        int row = wm * MT * 16 + mi * 16 + (l & 15);
        int c = kk * 4 + (l >> 4);
        int off = row * 128 + ((c ^ (row & 7)) * 16);
        ah[mi] = *(const bf16x8*)(sAh + off);
        al[mi] = *(const bf16x8*)(sAl + off);
      }
#pragma unroll
      for (int ni = 0; ni < NT; ++ni) {
        int row = wn * NT * 16 + ni * 16 + (l & 15);
        int c = kk * 4 + (l >> 4);
        int off = row * 128 + ((c ^ (row & 7)) * 16);
        bh[ni] = *(const bf16x8*)(sBh + off);
        bl[ni] = *(const bf16x8*)(sBl + off);
      }
#pragma unroll
      for (int mi = 0; mi < MT; ++mi)
#pragma unroll
        for (int ni = 0; ni < NT; ++ni) {
          acc[mi][ni] = __builtin_amdgcn_mfma_f32_16x16x32_bf16(ah[mi], bh[ni], acc[mi][ni], 0, 0, 0);
          acc[mi][ni] = __builtin_amdgcn_mfma_f32_16x16x32_bf16(ah[mi], bl[ni], acc[mi][ni], 0, 0, 0);
          acc[mi][ni] = __builtin_amdgcn_mfma_f32_16x16x32_bf16(al[mi], bh[ni], acc[mi][ni], 0, 0, 0);
        }
    }
    __syncthreads();
  }

  // ---------------- epilogues ----------------
  // C/D frag layout (verified m89): col = lane&15, row = (lane>>4)*4 + j
  if constexpr (EPI == 0) {
    // acc[mi][0] = Bm cols 0..15, acc[mi][1] = Cm cols 0..15
    int c = l & 15;
#pragma unroll
    for (int mi = 0; mi < MT; ++mi) {
#pragma unroll
      for (int j = 0; j < 4; ++j) {
        float bmv = acc[mi][0][j] + e0[c];
        float cmv = acc[mi][1][j] + e1[c];
        float p = bmv * cmv;
        p += __shfl_xor(p, 1, 64);
        p += __shfl_xor(p, 2, 64);
        p += __shfl_xor(p, 4, 64);
        p += __shfl_xor(p, 8, 64);
        if (c == 0) {
          int row = m0 + wm * MT * 16 + mi * 16 + (l >> 4) * 4 + j;
          outf[row] = p;
        }
      }
    }
  } else if constexpr (EPI == 1) {
#pragma unroll
    for (int mi = 0; mi < MT; ++mi) {
      int rbase = m0 + wm * MT * 16 + mi * 16 + (l >> 4) * 4;
#pragma unroll
      for (int ni = 0; ni < NT; ++ni) {
        int col = n0 + wn * NT * 16 + ni * 16 + (l & 15);
        float bdtc = e0[col];
        float dsk = e1[col];
#pragma unroll
        for (int j = 0; j < 4; ++j) {
          int row = rbase + j;
          size_t idx = (size_t)row * DMODEL + col;
          float v = acc[mi][ni][j] + bdtc;
          float sp = fmaxf(v, 0.0f) + __logf(1.0f + __expf(-fabsf(v)));
          float xnv = bf2f(e3h[idx]) + bf2f(e3l[idx]);
          float y = sp * xnv * e2[row] + xnv * dsk;
          unsigned short h = f2bf(y);
          outh[idx] = h;
          outl[idx] = f2bf(y - bf2f(h));
        }
      }
    }
  } else {
#pragma unroll
    for (int mi = 0; mi < MT; ++mi) {
      int rbase = m0 + wm * MT * 16 + mi * 16 + (l >> 4) * 4;
#pragma unroll
      for (int ni = 0; ni < NT; ++ni) {
        int col = n0 + wn * NT * 16 + ni * 16 + (l & 15);
        float bov = e0[col];
#pragma unroll
        for (int j = 0; j < 4; ++j) {
          int row = rbase + j;
          size_t idx = (size_t)row * DMODEL + col;
          outf[idx] = acc[mi][ni][j] + bov + e1[idx];
        }
      }
    }
  }
}

extern "C" void kernel_launch(void* const* d_in, const int* in_sizes, int n_in,
                              void* d_out, int out_size, void* d_ws, size_t ws_size,
                              hipStream_t stream) {
  const float* x = (const float*)d_in[0];
  const float* gamma = (const float*)d_in[1];
  const float* beta = (const float*)d_in[2];
  const float* Wb = (const float*)d_in[3];
  const float* bb = (const float*)d_in[4];
  const float* Wc = (const float*)d_in[5];
  const float* bc = (const float*)d_in[6];
  const float* Wdt = (const float*)d_in[7];
  const float* bdt = (const float*)d_in[8];
  const float* Dsk = (const float*)d_in[9];
  const float* Wo = (const float*)d_in[10];
  const float* bo = (const float*)d_in[11];
  float* out = (float*)d_out;

  char* ws = (char*)d_ws;
  size_t off = 0;
  auto alloc = [&](size_t bytes) {
    char* p = ws + off;
    off = (off + bytes + 255) & ~(size_t)255;
    return p;
  };
  unsigned short* XNH = (unsigned short*)alloc((size_t)BATCH * DMODEL * 2);
  unsigned short* XNL = (unsigned short*)alloc((size_t)BATCH * DMODEL * 2);
  unsigned short* YH  = (unsigned short*)alloc((size_t)BATCH * DMODEL * 2);
  unsigned short* YL  = (unsigned short*)alloc((size_t)BATCH * DMODEL * 2);
  unsigned short* WDTH = (unsigned short*)alloc((size_t)DMODEL * DMODEL * 2);
  unsigned short* WDTL = (unsigned short*)alloc((size_t)DMODEL * DMODEL * 2);
  unsigned short* WOH  = (unsigned short*)alloc((size_t)DMODEL * DMODEL * 2);
  unsigned short* WOL  = (unsigned short*)alloc((size_t)DMODEL * DMODEL * 2);
  unsigned short* WBCH = (unsigned short*)alloc((size_t)2 * NSTATE * DMODEL * 2);
  unsigned short* WBCL = (unsigned short*)alloc((size_t)2 * NSTATE * DMODEL * 2);
  float* S = (float*)alloc((size_t)BATCH * 4);

  // 1. split weights into bf16 hi/lo planes
  split_kernel<<<(DMODEL * DMODEL) / 256, 256, 0, stream>>>(Wdt, WDTH, WDTL, DMODEL * DMODEL);
  split_kernel<<<(DMODEL * DMODEL) / 256, 256, 0, stream>>>(Wo, WOH, WOL, DMODEL * DMODEL);
  split_kernel<<<(NSTATE * DMODEL) / 256, 256, 0, stream>>>(Wb, WBCH, WBCL, NSTATE * DMODEL);
  split_kernel<<<(NSTATE * DMODEL) / 256, 256, 0, stream>>>(
      Wc, WBCH + NSTATE * DMODEL, WBCL + NSTATE * DMODEL, NSTATE * DMODEL);

  // 2. LayerNorm + split
  ln_kernel<<<BATCH, 256, 0, stream>>>(x, gamma, beta, XNH, XNL);

  // 3. Bm/Cm -> s   (M=16384, N=32, K=1024)
  gemm_kernel<128, 32, 1, 4, 1, 2, 2, 0><<<BATCH / 128, 256, 0, stream>>>(
      XNH, XNL, WBCH, WBCL, bb, bc, nullptr, nullptr, nullptr, nullptr, nullptr, S, DMODEL);

  // 4. dt path GEMM + epilogue -> y (split)
  gemm_kernel<128, 128, 8, 2, 2, 4, 4, 1><<<(BATCH / 128) * 8, 256, 0, stream>>>(
      XNH, XNL, WDTH, WDTL, bdt, Dsk, S, XNH, XNL, YH, YL, nullptr, DMODEL);

  // 5. output GEMM + bias + residual
  gemm_kernel<128, 128, 8, 2, 2, 4, 4, 2><<<(BATCH / 128) * 8, 256, 0, stream>>>(
      YH, YL, WOH, WOL, bo, x, nullptr, nullptr, nullptr, nullptr, nullptr, out, DMODEL);
}